// Round 1
// baseline (653.226 us; speedup 1.0000x reference)
//
#include <hip/hip_runtime.h>
#include <math.h>

// Problem constants (from reference)
#define Hh   4
#define DKk  64
#define DVv  64
#define Mm   4
#define Bb   8
#define Qq   64
#define Kk   256
#define Dd   256
#define Nn   (Bb * Qq)          // 512
#define GNf  16.0f
#define EPSf 1e-5f

// ---------------------------------------------------------------------------
// 64-lane wave reduction (sum), result broadcast to all lanes
__device__ __forceinline__ float wred(float x) {
#pragma unroll
    for (int off = 32; off > 0; off >>= 1)
        x += __shfl_xor(x, off, 64);
    return x;
}

// ---------------------------------------------------------------------------
// Generic fp32 tiled GEMM: C[M,N] = scale*(A[M,K] @ W[K,N]) + bias[N]?
// BM=64, BN=64, BK=16, 256 threads, 4x4 microtile.
// Requires M%64==0, N%64==0, K%16==0.
__global__ __launch_bounds__(256) void gemm_f32(
    const float* __restrict__ A, const float* __restrict__ W,
    const float* __restrict__ bias, float* __restrict__ C,
    int Mr, int Nc, int Kc, float scale)
{
    __shared__ float As[64][17];
    __shared__ float Ws[16][65];
    const int tid = threadIdx.x;
    const int bm = blockIdx.y * 64;
    const int bn = blockIdx.x * 64;
    const int ty = tid >> 4, tx = tid & 15;
    const int aRow = tid >> 2;
    const int aCol = (tid & 3) * 4;
    const int wRow = tid >> 6;
    const int wCol = tid & 63;

    float acc[4][4] = {};

    for (int k0 = 0; k0 < Kc; k0 += 16) {
        const float4 av = *(const float4*)(A + (size_t)(bm + aRow) * Kc + k0 + aCol);
        As[aRow][aCol + 0] = av.x;
        As[aRow][aCol + 1] = av.y;
        As[aRow][aCol + 2] = av.z;
        As[aRow][aCol + 3] = av.w;
#pragma unroll
        for (int r = 0; r < 4; ++r)
            Ws[wRow + 4 * r][wCol] = W[(size_t)(k0 + wRow + 4 * r) * Nc + bn + wCol];
        __syncthreads();
#pragma unroll
        for (int kk = 0; kk < 16; ++kk) {
            float a[4], wv[4];
#pragma unroll
            for (int i = 0; i < 4; ++i) a[i] = As[ty * 4 + i][kk];
#pragma unroll
            for (int j = 0; j < 4; ++j) wv[j] = Ws[kk][tx * 4 + j];
#pragma unroll
            for (int i = 0; i < 4; ++i)
#pragma unroll
                for (int j = 0; j < 4; ++j)
                    acc[i][j] = fmaf(a[i], wv[j], acc[i][j]);
        }
        __syncthreads();
    }

#pragma unroll
    for (int i = 0; i < 4; ++i) {
#pragma unroll
        for (int j = 0; j < 4; ++j) {
            const int col = bn + tx * 4 + j;
            float v = acc[i][j] * scale;
            if (bias) v += bias[col];
            C[(size_t)(bm + ty * 4 + i) * Nc + col] = v;
        }
    }
}

// ---------------------------------------------------------------------------
// Small-N GEMM (N = 16 or 4): one thread per output element.
__global__ __launch_bounds__(256) void gemm_small(
    const float* __restrict__ A, const float* __restrict__ W,
    float* __restrict__ C, int Nc, int Kc)
{
    const int rpb = 256 / Nc;
    const int row = blockIdx.x * rpb + threadIdx.x / Nc;
    const int col = threadIdx.x % Nc;
    float acc = 0.f;
    for (int k = 0; k < Kc; ++k)
        acc = fmaf(A[(size_t)row * Kc + k], W[(size_t)k * Nc + col], acc);
    C[(size_t)row * Nc + col] = acc;
}

// ---------------------------------------------------------------------------
// Router: logits[n*K+t,:] = KV_r[b,t,:] + C_r[n,:]; write logits (output 1)
// and top-2 renormalized weights w_mem (N,K,M).
__global__ __launch_bounds__(256) void router_topk(
    const float* __restrict__ KV_r, const float* __restrict__ C_r,
    float* __restrict__ logits, float* __restrict__ wmem)
{
    const int idx = blockIdx.x * 256 + threadIdx.x;   // n*K + t
    const int n = idx >> 8;          // / Kk
    const int t = idx & 255;
    const int b = n / Qq;

    float l[4];
#pragma unroll
    for (int j = 0; j < 4; ++j)
        l[j] = KV_r[(size_t)(b * Kk + t) * 4 + j] + C_r[(size_t)n * 4 + j];

    *(float4*)(logits + (size_t)idx * 4) = make_float4(l[0], l[1], l[2], l[3]);

    // top-2 (ties: lower index first, matching jax.lax.top_k)
    int i1 = 0;
#pragma unroll
    for (int j = 1; j < 4; ++j) if (l[j] > l[i1]) i1 = j;
    int i2 = -1;
#pragma unroll
    for (int j = 0; j < 4; ++j) {
        if (j == i1) continue;
        if (i2 < 0 || l[j] > l[i2]) i2 = j;
    }
    const float mx = fmaxf(l[i1], l[i2]);
    const float e1 = expf(l[i1] - mx);
    const float e2 = expf(l[i2] - mx);
    const float inv = 1.f / (e1 + e2);
    float w[4] = {0.f, 0.f, 0.f, 0.f};
    w[i1] = e1 * inv;
    w[i2] = e2 * inv;
    *(float4*)(wmem + (size_t)idx * 4) = make_float4(w[0], w[1], w[2], w[3]);
}

// ---------------------------------------------------------------------------
// Main gated linear-attention recurrence, reverse sweep over t.
// Grid: 512 blocks (one per n). 256 threads: wave h = tid>>6, lane d = tid&63.
// Fuses q/k/v/gk reconstruction (KV part + cond part), 5 memories, RMSNorm.
__global__ __launch_bounds__(256) void mom_main(
    const float* __restrict__ KV_q, const float* __restrict__ KV_k,
    const float* __restrict__ KV_v, const float* __restrict__ KV_pre,
    const float* __restrict__ C_q, const float* __restrict__ C_k,
    const float* __restrict__ C_v, const float* __restrict__ C_pre,
    const int* __restrict__ mask, const float* __restrict__ wmem,
    const float* __restrict__ norm_w, float* __restrict__ o_out)
{
    const int n = blockIdx.x;
    const int b = n / Qq;
    const int h = threadIdx.x >> 6;
    const int d = threadIdx.x & 63;
    const int c = h * 64 + d;

    const float ql = KV_q[(size_t)(b * Kk + (Kk - 1)) * Dd + c] + C_q[(size_t)n * Dd + c];
    const float ck = C_k[(size_t)n * Dd + c];
    const float cv = C_v[(size_t)n * Dd + c];
    const float cp = C_pre[(size_t)n * Dd + c];

    float R0 = 0.f, R1 = 0.f, R2 = 0.f, R3 = 0.f, R4 = 0.f;
    float o = 0.f;

    for (int t = Kk - 1; t >= 0; --t) {
        const int bt = b * Kk + t;
        const float mf = (float)mask[bt];
        const float kk = (KV_k[(size_t)bt * Dd + c] + ck) * mf;
        const float vv = (KV_v[(size_t)bt * Dd + c] + cv) * mf;
        const float pre = KV_pre[(size_t)bt * Dd + c] + cp;
        // log_sigmoid(pre) = min(pre,0) - log1p(exp(-|pre|))
        const float ls = fminf(pre, 0.f) - log1pf(expf(-fabsf(pre)));
        const float gk = ls * (1.0f / GNf) * mf;
        const float p = ql * kk;

        const float4 w = *(const float4*)(wmem + ((size_t)n * Kk + t) * 4);

        // memory 0: sel = ones, wgt = ones
        o += wred(p * expf(R0)) * vv;
        R0 += gk;
        // experts (wave-uniform branches: w depends only on (n,t))
        if (w.x > 0.f) { o += wred(p * expf(R1)) * w.x * vv; R1 += gk; }
        if (w.y > 0.f) { o += wred(p * expf(R2)) * w.y * vv; R2 += gk; }
        if (w.z > 0.f) { o += wred(p * expf(R3)) * w.z * vv; R3 += gk; }
        if (w.w > 0.f) { o += wred(p * expf(R4)) * w.w * vv; R4 += gk; }
    }

    // RMSNorm over DV (per (n,h)), fused
    const float ms = wred(o * o) * (1.0f / 64.0f);
    const float sc = rsqrtf(ms + EPSf);
    o_out[(size_t)n * Dd + c] = o * sc * norm_w[d];
}

// ---------------------------------------------------------------------------
extern "C" void kernel_launch(void* const* d_in, const int* in_sizes, int n_in,
                              void* d_out, int out_size, void* d_ws, size_t ws_size,
                              hipStream_t stream)
{
    const float* query    = (const float*)d_in[0];   // (8,64,256)
    const float* keyval   = (const float*)d_in[1];   // (8,256,256)
    const int*   mask     = (const int*)  d_in[2];   // (8,256)
    const float* W_cond   = (const float*)d_in[3];   // (256,256)
    const float* W_q      = (const float*)d_in[4];   // (256,256)
    const float* W_k      = (const float*)d_in[5];   // (256,256)
    const float* W_v      = (const float*)d_in[6];   // (256,256)
    const float* W_gk1    = (const float*)d_in[7];   // (256,16)
    const float* W_gk2    = (const float*)d_in[8];   // (16,256)
    const float* b_gk2    = (const float*)d_in[9];   // (256,)
    const float* W_router = (const float*)d_in[10];  // (256,4)
    const float* norm_w   = (const float*)d_in[11];  // (64,)
    const float* W_o      = (const float*)d_in[12];  // (256,256)

    float* out    = (float*)d_out;        // (8,64,256) = 131072
    float* logits = out + Nn * Dd;        // (N*K, 4)   = 524288

    // workspace layout (floats)
    float* p = (float*)d_ws;
    float* cond   = p; p += Nn * Dd;            // 512*256
    float* C_q    = p; p += Nn * Dd;
    float* C_k    = p; p += Nn * Dd;
    float* C_v    = p; p += Nn * Dd;
    float* C_h1   = p; p += Nn * 16;
    float* C_r    = p; p += Nn * 4;
    float* C_pre  = p; p += Nn * Dd;
    float* KV_q   = p; p += Bb * Kk * Dd;       // 2048*256
    float* KV_k   = p; p += Bb * Kk * Dd;
    float* KV_v   = p; p += Bb * Kk * Dd;
    float* KV_pre = p; p += Bb * Kk * Dd;
    float* KV_h1  = p; p += Bb * Kk * 16;
    float* KV_r   = p; p += Bb * Kk * 4;
    float* wmem   = p; p += Nn * Kk * 4;
    float* o_nrm  = p; p += Nn * Dd;

    const dim3 blk(256);
    const dim3 gC(4, Nn / 64);          // (4,8)   for 512-row GEMMs
    const dim3 gKV(4, (Bb * Kk) / 64);  // (4,32)  for 2048-row GEMMs

    // cond = query @ W_cond (COND_SCALE = 1)
    gemm_f32<<<gC, blk, 0, stream>>>(query, W_cond, nullptr, cond, Nn, Dd, Dd, 1.0f);

    // cond-side projections
    gemm_f32<<<gC, blk, 0, stream>>>(cond, W_q, nullptr, C_q, Nn, Dd, Dd, 1.0f);
    gemm_f32<<<gC, blk, 0, stream>>>(cond, W_k, nullptr, C_k, Nn, Dd, Dd, 1.0f);
    gemm_f32<<<gC, blk, 0, stream>>>(cond, W_v, nullptr, C_v, Nn, Dd, Dd, 1.0f);
    gemm_small<<<Nn / (256 / 16), blk, 0, stream>>>(cond, W_gk1, C_h1, 16, Dd);
    gemm_small<<<Nn / (256 / 4), blk, 0, stream>>>(cond, W_router, C_r, 4, Dd);

    // keyval-side projections
    gemm_f32<<<gKV, blk, 0, stream>>>(keyval, W_q, nullptr, KV_q, Bb * Kk, Dd, Dd, 1.0f);
    gemm_f32<<<gKV, blk, 0, stream>>>(keyval, W_k, nullptr, KV_k, Bb * Kk, Dd, Dd, 1.0f);
    gemm_f32<<<gKV, blk, 0, stream>>>(keyval, W_v, nullptr, KV_v, Bb * Kk, Dd, Dd, 1.0f);
    gemm_small<<<(Bb * Kk) / (256 / 16), blk, 0, stream>>>(keyval, W_gk1, KV_h1, 16, Dd);
    gemm_small<<<(Bb * Kk) / (256 / 4), blk, 0, stream>>>(keyval, W_router, KV_r, 4, Dd);

    // second gate layer (bias lives on the cond side only)
    gemm_f32<<<gC, blk, 0, stream>>>(C_h1, W_gk2, b_gk2, C_pre, Nn, Dd, 16, 1.0f);
    gemm_f32<<<gKV, blk, 0, stream>>>(KV_h1, W_gk2, nullptr, KV_pre, Bb * Kk, Dd, 16, 1.0f);

    // router logits (output 1) + top-2 weights
    router_topk<<<(Nn * Kk) / 256, blk, 0, stream>>>(KV_r, C_r, logits, wmem);

    // main recurrence + RMSNorm
    mom_main<<<Nn, blk, 0, stream>>>(KV_q, KV_k, KV_v, KV_pre,
                                     C_q, C_k, C_v, C_pre,
                                     mask, wmem, norm_w, o_nrm);

    // output projection (output 0)
    gemm_f32<<<gC, blk, 0, stream>>>(o_nrm, W_o, nullptr, out, Nn, Dd, Dd, 1.0f);
}

// Round 2
// 318.755 us; speedup vs baseline: 2.0493x; 2.0493x over previous
//
#include <hip/hip_runtime.h>
#include <math.h>

// Problem constants (from reference)
#define Hh   4
#define DKk  64
#define DVv  64
#define Mm   4
#define Bb   8
#define Qq   64
#define Kk   256
#define Dd   256
#define Nn   (Bb * Qq)          // 512
#define GNf  16.0f
#define EPSf 1e-5f

// ---------------------------------------------------------------------------
// 64-lane wave reduction (sum), result broadcast to all lanes
__device__ __forceinline__ float wred(float x) {
#pragma unroll
    for (int off = 32; off > 0; off >>= 1)
        x += __shfl_xor(x, off, 64);
    return x;
}

// ---------------------------------------------------------------------------
// Generic fp32 tiled GEMM: C[M,N] = scale*(A[M,K] @ W[K,N]) + bias[N]?
// BM=64, BN=64, BK=16, 256 threads, 4x4 microtile. A has leading dim lda.
// Requires M%64==0, N%64==0, K%16==0, lda*4 bytes row stride, aCol 16B-aligned.
__global__ __launch_bounds__(256) void gemm_f32(
    const float* __restrict__ A, int lda, const float* __restrict__ W,
    const float* __restrict__ bias, float* __restrict__ C,
    int Nc, int Kc, float scale)
{
    __shared__ float As[64][17];
    __shared__ float Ws[16][65];
    const int tid = threadIdx.x;
    const int bm = blockIdx.y * 64;
    const int bn = blockIdx.x * 64;
    const int ty = tid >> 4, tx = tid & 15;
    const int aRow = tid >> 2;
    const int aCol = (tid & 3) * 4;
    const int wRow = tid >> 6;
    const int wCol = tid & 63;

    float acc[4][4] = {};

    for (int k0 = 0; k0 < Kc; k0 += 16) {
        const float4 av = *(const float4*)(A + (size_t)(bm + aRow) * lda + k0 + aCol);
        As[aRow][aCol + 0] = av.x;
        As[aRow][aCol + 1] = av.y;
        As[aRow][aCol + 2] = av.z;
        As[aRow][aCol + 3] = av.w;
#pragma unroll
        for (int r = 0; r < 4; ++r)
            Ws[wRow + 4 * r][wCol] = W[(size_t)(k0 + wRow + 4 * r) * Nc + bn + wCol];
        __syncthreads();
#pragma unroll
        for (int kk = 0; kk < 16; ++kk) {
            float a[4], wv[4];
#pragma unroll
            for (int i = 0; i < 4; ++i) a[i] = As[ty * 4 + i][kk];
#pragma unroll
            for (int j = 0; j < 4; ++j) wv[j] = Ws[kk][tx * 4 + j];
#pragma unroll
            for (int i = 0; i < 4; ++i)
#pragma unroll
                for (int j = 0; j < 4; ++j)
                    acc[i][j] = fmaf(a[i], wv[j], acc[i][j]);
        }
        __syncthreads();
    }

#pragma unroll
    for (int i = 0; i < 4; ++i) {
#pragma unroll
        for (int j = 0; j < 4; ++j) {
            const int col = bn + tx * 4 + j;
            float v = acc[i][j] * scale;
            if (bias) v += bias[col];
            C[(size_t)(bm + ty * 4 + i) * Nc + col] = v;
        }
    }
}

// ---------------------------------------------------------------------------
// Packed 20-col GEMM: C[row, 0..19] = A[row,:] @ Wgr (256x20), C has ldc=32.
// 320 threads = 5 waves, 16 rows/block.
__global__ __launch_bounds__(320) void gemm_small20(
    const float* __restrict__ A, int lda, const float* __restrict__ Wgr,
    float* __restrict__ C, int Kc)
{
    const int row = blockIdx.x * 16 + threadIdx.x / 20;
    const int col = threadIdx.x % 20;
    float acc = 0.f;
    for (int k = 0; k < Kc; ++k)
        acc = fmaf(A[(size_t)row * lda + k], Wgr[(size_t)k * 20 + col], acc);
    C[(size_t)row * 32 + col] = acc;
}

// ---------------------------------------------------------------------------
// Pack W_q|W_k|W_v -> Wqkv (256x768) and W_gk1|W_router -> Wgr (256x20)
__global__ __launch_bounds__(256) void pack_weights(
    const float* __restrict__ Wq, const float* __restrict__ Wk,
    const float* __restrict__ Wv, const float* __restrict__ Wg1,
    const float* __restrict__ Wr, float* __restrict__ Wqkv,
    float* __restrict__ Wgr)
{
    const int idx = blockIdx.x * 256 + threadIdx.x;
    if (idx < 256 * 768) {
        const int k = idx / 768, j = idx % 768;
        float v;
        if (j < 256)      v = Wq[(size_t)k * 256 + j];
        else if (j < 512) v = Wk[(size_t)k * 256 + j - 256];
        else              v = Wv[(size_t)k * 256 + j - 512];
        Wqkv[idx] = v;
    } else {
        const int r = idx - 256 * 768;
        if (r < 256 * 20) {
            const int k = r / 20, j = r % 20;
            Wgr[r] = (j < 16) ? Wg1[(size_t)k * 16 + j] : Wr[(size_t)k * 4 + j - 16];
        }
    }
}

// ---------------------------------------------------------------------------
// Router: logits[n*K+t,:] = KV_gr[b,t,16..19] + C_gr[n,16..19]; write logits
// (output 1) and top-2 renormalized weights w_mem (N,K,M).
__global__ __launch_bounds__(256) void router_topk(
    const float* __restrict__ KV_gr, const float* __restrict__ C_gr,
    float* __restrict__ logits, float* __restrict__ wmem)
{
    const int idx = blockIdx.x * 256 + threadIdx.x;   // n*K + t
    const int n = idx >> 8;
    const int t = idx & 255;
    const int b = n >> 6;

    const float4 kvr = *(const float4*)(KV_gr + (size_t)(b * Kk + t) * 32 + 16);
    const float4 cr  = *(const float4*)(C_gr  + (size_t)n * 32 + 16);
    float l[4] = {kvr.x + cr.x, kvr.y + cr.y, kvr.z + cr.z, kvr.w + cr.w};

    *(float4*)(logits + (size_t)idx * 4) = make_float4(l[0], l[1], l[2], l[3]);

    // top-2 (ties: lower index first, matching jax.lax.top_k)
    int i1 = 0;
#pragma unroll
    for (int j = 1; j < 4; ++j) if (l[j] > l[i1]) i1 = j;
    int i2 = -1;
#pragma unroll
    for (int j = 0; j < 4; ++j) {
        if (j == i1) continue;
        if (i2 < 0 || l[j] > l[i2]) i2 = j;
    }
    const float mx = fmaxf(l[i1], l[i2]);
    const float e1 = __expf(l[i1] - mx);
    const float e2 = __expf(l[i2] - mx);
    const float inv = 1.f / (e1 + e2);
    float w[4] = {0.f, 0.f, 0.f, 0.f};
    w[i1] = e1 * inv;
    w[i2] = e2 * inv;
    *(float4*)(wmem + (size_t)idx * 4) = make_float4(w[0], w[1], w[2], w[3]);
}

// ---------------------------------------------------------------------------
// Main gated linear-attention recurrence, reverse sweep over t.
// Grid: 512 blocks (one per n). 256 threads: wave = head h, lane = d.
// Single merged wave-reduction per t (linearity of wred over the 5 memories);
// multiplicative decay state E_e (one exp per t instead of one per memory).
__global__ __launch_bounds__(256) void mom_main(
    const float* __restrict__ KV_qkv, const float* __restrict__ KV_pre,
    const float* __restrict__ C_qkv,  const float* __restrict__ C_pre,
    const int* __restrict__ mask, const float* __restrict__ wmem,
    const float* __restrict__ norm_w, float* __restrict__ o_out)
{
    const int n = blockIdx.x;
    const int b = n >> 6;              // n / Qq
    const int c = threadIdx.x;         // = h*64 + d  (Dd == blockDim)
    const int d = c & 63;

    const float ql = KV_qkv[(size_t)(b * Kk + Kk - 1) * 768 + c] + C_qkv[(size_t)n * 768 + c];
    const float ck = C_qkv[(size_t)n * 768 + 256 + c];
    const float cv = C_qkv[(size_t)n * 768 + 512 + c];
    const float cp = C_pre[(size_t)n * Dd + c];

    const float* pk = KV_qkv + (size_t)b * Kk * 768 + 256 + c;
    const float* pv = KV_qkv + (size_t)b * Kk * 768 + 512 + c;
    const float* pp = KV_pre + (size_t)b * Kk * Dd + c;
    const int*   pm = mask + b * Kk;
    const float4* pw = (const float4*)wmem + (size_t)n * Kk;

    float E0 = 1.f, E1 = 1.f, E2 = 1.f, E3 = 1.f, E4 = 1.f;
    float o = 0.f;

#pragma unroll 4
    for (int t = Kk - 1; t >= 0; --t) {
        const float mf  = (float)pm[t];
        const float kk  = (pk[(size_t)t * 768] + ck) * mf;
        const float vv  = (pv[(size_t)t * 768] + cv) * mf;
        const float pre = pp[(size_t)t * Dd] + cp;
        const float4 w  = pw[t];

        // dgk = exp(log_sigmoid(pre)/GN) if masked-in else 1
        const float ls = fminf(pre, 0.f) - __logf(1.f + __expf(-fabsf(pre)));
        float dg = __expf(ls * (1.0f / GNf));
        dg = (mf != 0.f) ? dg : 1.f;

        // merged reduction: o += wred(q*k * (E0 + sum_e w_e E_e)) * v
        const float zf = E0 + w.x * E1 + w.y * E2 + w.z * E3 + w.w * E4;
        const float s = wred(ql * kk * zf);
        o = fmaf(s, vv, o);

        // branchless decay-state updates (selection == w_e > 0)
        E0 *= dg;
        E1 *= (w.x > 0.f) ? dg : 1.f;
        E2 *= (w.y > 0.f) ? dg : 1.f;
        E3 *= (w.z > 0.f) ? dg : 1.f;
        E4 *= (w.w > 0.f) ? dg : 1.f;
    }

    // RMSNorm over DV (per (n,h)), fused
    const float ms = wred(o * o) * (1.0f / 64.0f);
    o_out[(size_t)n * Dd + c] = o * rsqrtf(ms + EPSf) * norm_w[d];
}

// ---------------------------------------------------------------------------
extern "C" void kernel_launch(void* const* d_in, const int* in_sizes, int n_in,
                              void* d_out, int out_size, void* d_ws, size_t ws_size,
                              hipStream_t stream)
{
    const float* query    = (const float*)d_in[0];   // (8,64,256)
    const float* keyval   = (const float*)d_in[1];   // (8,256,256)
    const int*   mask     = (const int*)  d_in[2];   // (8,256)
    const float* W_cond   = (const float*)d_in[3];   // (256,256)
    const float* W_q      = (const float*)d_in[4];   // (256,256)
    const float* W_k      = (const float*)d_in[5];   // (256,256)
    const float* W_v      = (const float*)d_in[6];   // (256,256)
    const float* W_gk1    = (const float*)d_in[7];   // (256,16)
    const float* W_gk2    = (const float*)d_in[8];   // (16,256)
    const float* b_gk2    = (const float*)d_in[9];   // (256,)
    const float* W_router = (const float*)d_in[10];  // (256,4)
    const float* norm_w   = (const float*)d_in[11];  // (64,)
    const float* W_o      = (const float*)d_in[12];  // (256,256)

    float* out    = (float*)d_out;        // (8,64,256) = 131072
    float* logits = out + Nn * Dd;        // (N*K, 4)   = 524288

    // workspace layout (floats)
    float* p = (float*)d_ws;
    float* cond   = p; p += Nn * Dd;            // 512*256
    float* C_qkv  = p; p += Nn * 768;
    float* C_gr   = p; p += Nn * 32;            // cols 0..15 = h1, 16..19 = router
    float* C_pre  = p; p += Nn * Dd;
    float* KV_qkv = p; p += Bb * Kk * 768;
    float* KV_gr  = p; p += Bb * Kk * 32;
    float* KV_pre = p; p += Bb * Kk * Dd;
    float* Wqkv   = p; p += Dd * 768;
    float* Wgr    = p; p += Dd * 20;
    float* wmem   = p; p += Nn * Kk * 4;
    float* o_nrm  = p; p += Nn * Dd;

    const dim3 blk(256);
    const dim3 gC1(4, Nn / 64);           // (4,8)   512-row, N=256
    const dim3 gC3(12, Nn / 64);          // (12,8)  512-row, N=768
    const dim3 gKV1(4, (Bb * Kk) / 64);   // (4,32)  2048-row, N=256
    const dim3 gKV3(12, (Bb * Kk) / 64);  // (12,32) 2048-row, N=768

    // pack fused weights
    pack_weights<<<788, blk, 0, stream>>>(W_q, W_k, W_v, W_gk1, W_router, Wqkv, Wgr);

    // cond = query @ W_cond (COND_SCALE = 1)
    gemm_f32<<<gC1, blk, 0, stream>>>(query, Dd, W_cond, nullptr, cond, Dd, Dd, 1.0f);

    // fused q|k|v projections
    gemm_f32<<<gC3, blk, 0, stream>>>(cond, Dd, Wqkv, nullptr, C_qkv, 768, Dd, 1.0f);
    gemm_f32<<<gKV3, blk, 0, stream>>>(keyval, Dd, Wqkv, nullptr, KV_qkv, 768, Dd, 1.0f);

    // fused gate-hidden|router projections
    gemm_small20<<<Nn / 16, dim3(320), 0, stream>>>(cond, Dd, Wgr, C_gr, Dd);
    gemm_small20<<<(Bb * Kk) / 16, dim3(320), 0, stream>>>(keyval, Dd, Wgr, KV_gr, Dd);

    // second gate layer (bias lives on the cond side only)
    gemm_f32<<<gC1, blk, 0, stream>>>(C_gr, 32, W_gk2, b_gk2, C_pre, Dd, 16, 1.0f);
    gemm_f32<<<gKV1, blk, 0, stream>>>(KV_gr, 32, W_gk2, nullptr, KV_pre, Dd, 16, 1.0f);

    // router logits (output 1) + top-2 weights
    router_topk<<<(Nn * Kk) / 256, blk, 0, stream>>>(KV_gr, C_gr, logits, wmem);

    // main recurrence + RMSNorm
    mom_main<<<Nn, blk, 0, stream>>>(KV_qkv, KV_pre, C_qkv, C_pre,
                                     mask, wmem, norm_w, o_nrm);

    // output projection (output 0)
    gemm_f32<<<gC1, blk, 0, stream>>>(o_nrm, Dd, W_o, nullptr, out, Dd, Dd, 1.0f);
}

// Round 3
// 220.357 us; speedup vs baseline: 2.9644x; 1.4465x over previous
//
#include <hip/hip_runtime.h>
#include <math.h>

// Problem constants (from reference)
#define Hh   4
#define DKk  64
#define DVv  64
#define Mm   4
#define Bb   8
#define Qq   64
#define Kk   256
#define Dd   256
#define Nn   (Bb * Qq)          // 512
#define GNf  16.0f
#define EPSf 1e-5f
#define WB   1088               // packed width: q(256)|k(256)|v(256)|pre(256)|r(4)|pad(60)

// ---------------------------------------------------------------------------
// 64-lane wave reduction (sum), result broadcast to all lanes
__device__ __forceinline__ float wred(float x) {
#pragma unroll
    for (int off = 32; off > 0; off >>= 1)
        x += __shfl_xor(x, off, 64);
    return x;
}

// ---------------------------------------------------------------------------
// Pack Wb (256 x 1088) = [W_q | W_k | W_v | W_gk1@W_gk2 | W_router | 0-pad]
__global__ __launch_bounds__(256) void pack_wb(
    const float* __restrict__ Wq, const float* __restrict__ Wk,
    const float* __restrict__ Wv, const float* __restrict__ Wg1,
    const float* __restrict__ Wg2, const float* __restrict__ Wr,
    float* __restrict__ Wb)
{
    const int idx = blockIdx.x * 256 + threadIdx.x;   // < 256*1088
    const int k = idx / WB, j = idx % WB;
    float v;
    if (j < 256)       v = Wq[(size_t)k * 256 + j];
    else if (j < 512)  v = Wk[(size_t)k * 256 + j - 256];
    else if (j < 768)  v = Wv[(size_t)k * 256 + j - 512];
    else if (j < 1024) {
        const int c = j - 768;
        float s = 0.f;
#pragma unroll
        for (int i = 0; i < 16; ++i)
            s = fmaf(Wg1[(size_t)k * 16 + i], Wg2[(size_t)i * 256 + c], s);
        v = s;                                   // Wg = W_gk1 @ W_gk2
    }
    else if (j < 1028) v = Wr[(size_t)k * 4 + (j - 1024)];
    else               v = 0.f;
    Wb[idx] = v;
}

// ---------------------------------------------------------------------------
// fp32 tiled GEMM: C[M,N] = A[M,K] @ W[K,N].
// BM=64, BN=64, BK=16, 256 threads, 4x4 microtile. Requires M%64==0, N%64==0.
__global__ __launch_bounds__(256) void gemm_f32(
    const float* __restrict__ A, int lda, const float* __restrict__ W,
    float* __restrict__ C, int Nc, int Kc)
{
    __shared__ float As[64][17];
    __shared__ float Ws[16][65];
    const int tid = threadIdx.x;
    const int bm = blockIdx.y * 64;
    const int bn = blockIdx.x * 64;
    const int ty = tid >> 4, tx = tid & 15;
    const int aRow = tid >> 2;
    const int aCol = (tid & 3) * 4;
    const int wRow = tid >> 6;
    const int wCol = tid & 63;

    float acc[4][4] = {};

    for (int k0 = 0; k0 < Kc; k0 += 16) {
        const float4 av = *(const float4*)(A + (size_t)(bm + aRow) * lda + k0 + aCol);
        As[aRow][aCol + 0] = av.x;
        As[aRow][aCol + 1] = av.y;
        As[aRow][aCol + 2] = av.z;
        As[aRow][aCol + 3] = av.w;
#pragma unroll
        for (int r = 0; r < 4; ++r)
            Ws[wRow + 4 * r][wCol] = W[(size_t)(k0 + wRow + 4 * r) * Nc + bn + wCol];
        __syncthreads();
#pragma unroll
        for (int kk = 0; kk < 16; ++kk) {
            float a[4], wv[4];
#pragma unroll
            for (int i = 0; i < 4; ++i) a[i] = As[ty * 4 + i][kk];
#pragma unroll
            for (int j = 0; j < 4; ++j) wv[j] = Ws[kk][tx * 4 + j];
#pragma unroll
            for (int i = 0; i < 4; ++i)
#pragma unroll
                for (int j = 0; j < 4; ++j)
                    acc[i][j] = fmaf(a[i], wv[j], acc[i][j]);
        }
        __syncthreads();
    }

#pragma unroll
    for (int i = 0; i < 4; ++i)
#pragma unroll
        for (int j = 0; j < 4; ++j)
            C[(size_t)(bm + ty * 4 + i) * Nc + bn + tx * 4 + j] = acc[i][j];
}

// ---------------------------------------------------------------------------
// Fused cond-side + router + gated linear-attention recurrence + RMSNorm +
// output projection. One block per n (512 blocks, 256 threads).
// Thread j owns output dim j throughout; wave = head h (j>>6), lane = d (j&63).
__global__ __launch_bounds__(256) void mom_fused(
    const float* __restrict__ query, const float* __restrict__ W_cond,
    const float* __restrict__ Wb,    const float* __restrict__ b_gk2,
    const float* __restrict__ KVb,   const int* __restrict__ mask,
    const float* __restrict__ W_o,   const float* __restrict__ norm_w,
    float* __restrict__ out, float* __restrict__ logits)
{
    __shared__ float  qrow[256];
    __shared__ float  crow[256];
    __shared__ float4 wm[256];
    __shared__ float  rc4[4];
    __shared__ float  onorm[256];

    const int n = blockIdx.x;
    const int b = n >> 6;            // n / Qq
    const int j = threadIdx.x;
    const int lane = j & 63;
    const int wv = j >> 6;

    // ---- cond row: cond = query[n,:] @ W_cond (COND_SCALE = 1)
    qrow[j] = query[(size_t)n * Dd + j];
    __syncthreads();
    {
        float acc = 0.f;
#pragma unroll 8
        for (int k = 0; k < Dd; ++k)
            acc = fmaf(qrow[k], W_cond[(size_t)k * Dd + j], acc);
        crow[j] = acc;
    }
    __syncthreads();

    // ---- fused cond-side projections: columns j, 256+j, 512+j, 768+j of Wb
    float qc = 0.f, kc = 0.f, vc = 0.f, pc = 0.f;
#pragma unroll 4
    for (int k = 0; k < Dd; ++k) {
        const float a = crow[k];
        const float* wp = Wb + (size_t)k * WB + j;
        qc = fmaf(a, wp[0],   qc);
        kc = fmaf(a, wp[256], kc);
        vc = fmaf(a, wp[512], vc);
        pc = fmaf(a, wp[768], pc);
    }
    pc += b_gk2[j];

    // ---- cond-side router logits: wave wv computes rc[wv] via wave reduction
    {
        float r = 0.f;
#pragma unroll
        for (int i = 0; i < 4; ++i) {
            const int k = lane + 64 * i;
            r = fmaf(crow[k], Wb[(size_t)k * WB + 1024 + wv], r);
        }
        r = wred(r);
        if (lane == 0) rc4[wv] = r;
    }
    __syncthreads();

    // ---- router top-2 for t = j; write logits (output 1) and weights to LDS
    {
        const float4 kvr = *(const float4*)(KVb + (size_t)(b * Kk + j) * WB + 1024);
        float l[4] = {kvr.x + rc4[0], kvr.y + rc4[1], kvr.z + rc4[2], kvr.w + rc4[3]};
        *(float4*)(logits + ((size_t)n * Kk + j) * 4) = make_float4(l[0], l[1], l[2], l[3]);

        int i1 = 0;
#pragma unroll
        for (int q = 1; q < 4; ++q) if (l[q] > l[i1]) i1 = q;
        int i2 = -1;
#pragma unroll
        for (int q = 0; q < 4; ++q) {
            if (q == i1) continue;
            if (i2 < 0 || l[q] > l[i2]) i2 = q;
        }
        const float mx = fmaxf(l[i1], l[i2]);
        const float e1 = __expf(l[i1] - mx);
        const float e2 = __expf(l[i2] - mx);
        const float inv = 1.f / (e1 + e2);
        float w[4] = {0.f, 0.f, 0.f, 0.f};
        w[i1] = e1 * inv;
        w[i2] = e2 * inv;
        wm[j] = make_float4(w[0], w[1], w[2], w[3]);
    }
    __syncthreads();

    // ---- reverse-sweep recurrence (merged reduction, multiplicative decay)
    const float ql = KVb[(size_t)(b * Kk + Kk - 1) * WB + j] + qc;
    const float* pk = KVb + (size_t)b * Kk * WB + 256 + j;
    const float* pv = KVb + (size_t)b * Kk * WB + 512 + j;
    const float* pp = KVb + (size_t)b * Kk * WB + 768 + j;
    const int*   pm = mask + b * Kk;

    float E0 = 1.f, E1 = 1.f, E2 = 1.f, E3 = 1.f, E4 = 1.f;
    float o = 0.f;

#pragma unroll 4
    for (int t = Kk - 1; t >= 0; --t) {
        const float mf  = (float)pm[t];
        const float kk  = (pk[(size_t)t * WB] + kc) * mf;
        const float vv  = (pv[(size_t)t * WB] + vc) * mf;
        const float pre = pp[(size_t)t * WB] + pc;
        const float4 w  = wm[t];   // LDS broadcast

        // dgk = exp(log_sigmoid(pre)/GN) if masked-in else 1
        const float ls = fminf(pre, 0.f) - __logf(1.f + __expf(-fabsf(pre)));
        float dg = __expf(ls * (1.0f / GNf));
        dg = (mf != 0.f) ? dg : 1.f;

        // merged reduction over the 5 memories (linearity of wred)
        const float zf = E0 + w.x * E1 + w.y * E2 + w.z * E3 + w.w * E4;
        const float s = wred(ql * kk * zf);
        o = fmaf(s, vv, o);

        E0 *= dg;
        E1 *= (w.x > 0.f) ? dg : 1.f;
        E2 *= (w.y > 0.f) ? dg : 1.f;
        E3 *= (w.z > 0.f) ? dg : 1.f;
        E4 *= (w.w > 0.f) ? dg : 1.f;
    }

    // ---- fused RMSNorm over DV (per head = per wave)
    const float ms = wred(o * o) * (1.0f / 64.0f);
    onorm[j] = o * rsqrtf(ms + EPSf) * norm_w[lane];
    __syncthreads();

    // ---- fused output projection: out[n,j] = onorm . W_o[:,j]
    {
        float acc = 0.f;
#pragma unroll 8
        for (int k = 0; k < Dd; ++k)
            acc = fmaf(onorm[k], W_o[(size_t)k * Dd + j], acc);
        out[(size_t)n * Dd + j] = acc;
    }
}

// ---------------------------------------------------------------------------
extern "C" void kernel_launch(void* const* d_in, const int* in_sizes, int n_in,
                              void* d_out, int out_size, void* d_ws, size_t ws_size,
                              hipStream_t stream)
{
    const float* query    = (const float*)d_in[0];   // (8,64,256)
    const float* keyval   = (const float*)d_in[1];   // (8,256,256)
    const int*   mask     = (const int*)  d_in[2];   // (8,256)
    const float* W_cond   = (const float*)d_in[3];   // (256,256)
    const float* W_q      = (const float*)d_in[4];   // (256,256)
    const float* W_k      = (const float*)d_in[5];   // (256,256)
    const float* W_v      = (const float*)d_in[6];   // (256,256)
    const float* W_gk1    = (const float*)d_in[7];   // (256,16)
    const float* W_gk2    = (const float*)d_in[8];   // (16,256)
    const float* b_gk2    = (const float*)d_in[9];   // (256,)
    const float* W_router = (const float*)d_in[10];  // (256,4)
    const float* norm_w   = (const float*)d_in[11];  // (64,)
    const float* W_o      = (const float*)d_in[12];  // (256,256)

    float* out    = (float*)d_out;        // (8,64,256) = 131072
    float* logits = out + Nn * Dd;        // (N*K, 4)   = 524288

    // workspace layout (floats)
    float* p = (float*)d_ws;
    float* Wb  = p; p += Dd * WB;          // 256 x 1088 packed weights
    float* KVb = p; p += Bb * Kk * WB;     // 2048 x 1088 packed KV projections

    // 1) pack fused weight matrix (includes Wg = W_gk1 @ W_gk2)
    pack_wb<<<(Dd * WB) / 256, dim3(256), 0, stream>>>(
        W_q, W_k, W_v, W_gk1, W_gk2, W_router, Wb);

    // 2) entire KV side in one GEMM: KVb = keyval @ Wb  (2048 x 1088 x 256)
    gemm_f32<<<dim3(WB / 64, (Bb * Kk) / 64), dim3(256), 0, stream>>>(
        keyval, Dd, Wb, KVb, WB, Dd);

    // 3) everything else fused: cond side + router + recurrence + norm + W_o
    mom_fused<<<Nn, dim3(256), 0, stream>>>(
        query, W_cond, Wb, b_gk2, KVb, mask, W_o, norm_w, out, logits);
}

// Round 4
// 196.829 us; speedup vs baseline: 3.3187x; 1.1195x over previous
//
#include <hip/hip_runtime.h>
#include <math.h>

// Problem constants (from reference)
#define Hh   4
#define Bb   8
#define Qq   64
#define Kk   256
#define Dd   256
#define Nn   (Bb * Qq)          // 512
#define GNf  16.0f
#define EPSf 1e-5f
#define WB   1088               // packed width: q(256)|k(256)|v(256)|pre(256)|r(4)|pad(60)

// ---------------------------------------------------------------------------
// 64-lane wave reduction (sum), result broadcast to all lanes
__device__ __forceinline__ float wred(float x) {
#pragma unroll
    for (int off = 32; off > 0; off >>= 1)
        x += __shfl_xor(x, off, 64);
    return x;
}

// ---------------------------------------------------------------------------
// Pack Wb (256 x 1088) = [W_q | W_k | W_v | W_gk1@W_gk2 | W_router | 0-pad]
__global__ __launch_bounds__(256) void pack_wb(
    const float* __restrict__ Wq, const float* __restrict__ Wk,
    const float* __restrict__ Wv, const float* __restrict__ Wg1,
    const float* __restrict__ Wg2, const float* __restrict__ Wr,
    float* __restrict__ Wb)
{
    const int idx = blockIdx.x * 256 + threadIdx.x;   // < 256*1088
    const int k = idx / WB, j = idx % WB;
    float v;
    if (j < 256)       v = Wq[(size_t)k * 256 + j];
    else if (j < 512)  v = Wk[(size_t)k * 256 + j - 256];
    else if (j < 768)  v = Wv[(size_t)k * 256 + j - 512];
    else if (j < 1024) {
        const int c = j - 768;
        float s = 0.f;
#pragma unroll
        for (int i = 0; i < 16; ++i)
            s = fmaf(Wg1[(size_t)k * 16 + i], Wg2[(size_t)i * 256 + c], s);
        v = s;                                   // Wg = W_gk1 @ W_gk2
    }
    else if (j < 1028) v = Wr[(size_t)k * 4 + (j - 1024)];
    else               v = 0.f;
    Wb[idx] = v;
}

// ---------------------------------------------------------------------------
// gemm1: one launch computing BOTH   KVb = keyval @ Wb   (2048 x 1088)
//                            and     cond = query  @ W_cond (512 x 256).
// Flattened block id -> (region, bm, bn); zero wasted blocks (576 total).
// BM=BN=64, BK=16, 256 threads, 4x4 microtile.
__global__ __launch_bounds__(256) void gemm1(
    const float* __restrict__ keyval, const float* __restrict__ query,
    const float* __restrict__ Wb, const float* __restrict__ W_cond,
    float* __restrict__ KVb, float* __restrict__ cond)
{
    __shared__ float As[64][17];
    __shared__ float Ws[16][65];
    const int tid = threadIdx.x;

    int id = blockIdx.x;
    const float* A; const float* Bp; float* C;
    int ldb, ldc;
    if (id < 544) {                       // keyval @ Wb
        const int bm = (id / 17) * 64, bn = (id % 17) * 64;
        A  = keyval + (size_t)bm * Dd;
        Bp = Wb + bn;        ldb = WB;
        C  = KVb + (size_t)bm * WB + bn;  ldc = WB;
    } else {                              // query @ W_cond
        id -= 544;
        const int bm = (id >> 2) * 64, bn = (id & 3) * 64;
        A  = query + (size_t)bm * Dd;
        Bp = W_cond + bn;    ldb = Dd;
        C  = cond + (size_t)bm * Dd + bn; ldc = Dd;
    }

    const int ty = tid >> 4, tx = tid & 15;
    const int aRow = tid >> 2, aCol = (tid & 3) * 4;
    const int wRow = tid >> 6, wCol = tid & 63;

    float acc[4][4] = {};

    for (int k0 = 0; k0 < Dd; k0 += 16) {
        const float4 av = *(const float4*)(A + (size_t)aRow * Dd + k0 + aCol);
        As[aRow][aCol + 0] = av.x;
        As[aRow][aCol + 1] = av.y;
        As[aRow][aCol + 2] = av.z;
        As[aRow][aCol + 3] = av.w;
#pragma unroll
        for (int r = 0; r < 4; ++r)
            Ws[wRow + 4 * r][wCol] = Bp[(size_t)(k0 + wRow + 4 * r) * ldb + wCol];
        __syncthreads();
#pragma unroll
        for (int kk = 0; kk < 16; ++kk) {
            float a[4], wv[4];
#pragma unroll
            for (int i = 0; i < 4; ++i) a[i] = As[ty * 4 + i][kk];
#pragma unroll
            for (int j = 0; j < 4; ++j) wv[j] = Ws[kk][tx * 4 + j];
#pragma unroll
            for (int i = 0; i < 4; ++i)
#pragma unroll
                for (int j = 0; j < 4; ++j)
                    acc[i][j] = fmaf(a[i], wv[j], acc[i][j]);
        }
        __syncthreads();
    }

#pragma unroll
    for (int i = 0; i < 4; ++i)
#pragma unroll
        for (int j = 0; j < 4; ++j)
            C[(size_t)(ty * 4 + i) * ldc + tx * 4 + j] = acc[i][j];
}

// ---------------------------------------------------------------------------
// gemm2: Cb = cond @ Wb  (512 x 1088 x 256). Same tile scheme.
__global__ __launch_bounds__(256) void gemm2(
    const float* __restrict__ cond, const float* __restrict__ Wb,
    float* __restrict__ Cb)
{
    __shared__ float As[64][17];
    __shared__ float Ws[16][65];
    const int tid = threadIdx.x;
    const int bm = blockIdx.y * 64;
    const int bn = blockIdx.x * 64;
    const int ty = tid >> 4, tx = tid & 15;
    const int aRow = tid >> 2, aCol = (tid & 3) * 4;
    const int wRow = tid >> 6, wCol = tid & 63;

    float acc[4][4] = {};

    for (int k0 = 0; k0 < Dd; k0 += 16) {
        const float4 av = *(const float4*)(cond + (size_t)(bm + aRow) * Dd + k0 + aCol);
        As[aRow][aCol + 0] = av.x;
        As[aRow][aCol + 1] = av.y;
        As[aRow][aCol + 2] = av.z;
        As[aRow][aCol + 3] = av.w;
#pragma unroll
        for (int r = 0; r < 4; ++r)
            Ws[wRow + 4 * r][wCol] = Wb[(size_t)(k0 + wRow + 4 * r) * WB + bn + wCol];
        __syncthreads();
#pragma unroll
        for (int kk = 0; kk < 16; ++kk) {
            float a[4], wv[4];
#pragma unroll
            for (int i = 0; i < 4; ++i) a[i] = As[ty * 4 + i][kk];
#pragma unroll
            for (int j = 0; j < 4; ++j) wv[j] = Ws[kk][tx * 4 + j];
#pragma unroll
            for (int i = 0; i < 4; ++i)
#pragma unroll
                for (int j = 0; j < 4; ++j)
                    acc[i][j] = fmaf(a[i], wv[j], acc[i][j]);
        }
        __syncthreads();
    }

#pragma unroll
    for (int i = 0; i < 4; ++i)
#pragma unroll
        for (int j = 0; j < 4; ++j)
            Cb[(size_t)(bm + ty * 4 + i) * WB + bn + tx * 4 + j] = acc[i][j];
}

// ---------------------------------------------------------------------------
// Fused router + gated linear-attention recurrence + RMSNorm + W_o projection.
// One block per n (512 blocks, 256 threads). Thread j owns channel c = j;
// wave = head h (j>>6), lane = d (j&63).
// t-loop processes 16-t tiles: phase A computes P[t,c] into a per-wave LDS
// tile (no cross-lane ops); phase B does a bulk transpose-reduce (4x
// ds_read_b128 + 2 shfl + LDS broadcast) instead of 16 serial wave reductions.
__global__ __launch_bounds__(256) void mom_fused(
    const float* __restrict__ KVb, const float* __restrict__ Cb,
    const float* __restrict__ b_gk2, const int* __restrict__ mask,
    const float* __restrict__ W_o, const float* __restrict__ norm_w,
    float* __restrict__ out, float* __restrict__ logits)
{
    __shared__ float4 wm[Kk];
    __shared__ float  Ptile[4][16][68];   // per-wave 16t x 64c, padded row
    __shared__ float  sbuf[4][16];
    __shared__ float  onorm[Dd];

    const int n = blockIdx.x;
    const int b = n >> 6;            // n / Qq
    const int j = threadIdx.x;
    const int lane = j & 63;
    const int wv = j >> 6;

    // ---- per-n cond-side values (precomputed by gemm2)
    const float qc = Cb[(size_t)n * WB + j];
    const float kc = Cb[(size_t)n * WB + 256 + j];
    const float vc = Cb[(size_t)n * WB + 512 + j];
    const float pc = Cb[(size_t)n * WB + 768 + j] + b_gk2[j];
    const float4 rc = *(const float4*)(Cb + (size_t)n * WB + 1024);

    // ---- router top-2 for t = j; write logits (output 1) and weights to LDS
    {
        const float4 kvr = *(const float4*)(KVb + (size_t)(b * Kk + j) * WB + 1024);
        float l[4] = {kvr.x + rc.x, kvr.y + rc.y, kvr.z + rc.z, kvr.w + rc.w};
        *(float4*)(logits + ((size_t)n * Kk + j) * 4) = make_float4(l[0], l[1], l[2], l[3]);

        int i1 = 0;
#pragma unroll
        for (int q = 1; q < 4; ++q) if (l[q] > l[i1]) i1 = q;
        int i2 = -1;
#pragma unroll
        for (int q = 0; q < 4; ++q) {
            if (q == i1) continue;
            if (i2 < 0 || l[q] > l[i2]) i2 = q;
        }
        const float mx = fmaxf(l[i1], l[i2]);
        const float e1 = __expf(l[i1] - mx);
        const float e2 = __expf(l[i2] - mx);
        const float inv = 1.f / (e1 + e2);
        float w[4] = {0.f, 0.f, 0.f, 0.f};
        w[i1] = e1 * inv;
        w[i2] = e2 * inv;
        wm[j] = make_float4(w[0], w[1], w[2], w[3]);
    }
    __syncthreads();

    // ---- reverse-sweep recurrence in 16-t tiles
    const float ql = KVb[(size_t)(b * Kk + Kk - 1) * WB + j] + qc;
    const float* pk = KVb + (size_t)b * Kk * WB + 256 + j;
    const float* pv = KVb + (size_t)b * Kk * WB + 512 + j;
    const float* pp = KVb + (size_t)b * Kk * WB + 768 + j;
    const int*   pm = mask + b * Kk;

    float E0 = 1.f, E1 = 1.f, E2 = 1.f, E3 = 1.f, E4 = 1.f;
    float o = 0.f;
    const int tl = lane & 15, qq = lane >> 4;

    for (int t0 = Kk - 16; t0 >= 0; t0 -= 16) {
        float vreg[16];
        // phase A: per-t P into LDS tile, no cross-lane ops
#pragma unroll
        for (int i = 0; i < 16; ++i) {
            const int t = t0 + 15 - i;         // descending t
            const float mf  = (float)pm[t];
            const float kk  = (pk[(size_t)t * WB] + kc) * mf;
            const float vvv = (pv[(size_t)t * WB] + vc) * mf;
            const float pre = pp[(size_t)t * WB] + pc;
            const float4 w  = wm[t];

            const float ls = fminf(pre, 0.f) - __logf(1.f + __expf(-fabsf(pre)));
            float dg = __expf(ls * (1.0f / GNf));
            dg = (mf != 0.f) ? dg : 1.f;

            const float zf = E0 + w.x * E1 + w.y * E2 + w.z * E3 + w.w * E4;
            Ptile[wv][i][lane] = ql * kk * zf;
            vreg[i] = vvv;

            E0 *= dg;
            E1 *= (w.x > 0.f) ? dg : 1.f;
            E2 *= (w.y > 0.f) ? dg : 1.f;
            E3 *= (w.z > 0.f) ? dg : 1.f;
            E4 *= (w.w > 0.f) ? dg : 1.f;
        }
        __builtin_amdgcn_wave_barrier();

        // phase B (wave-local): s[i] = sum_c P[i][c]
        float s = 0.f;
#pragma unroll
        for (int r = 0; r < 4; ++r) {
            const float4 p4 = *(const float4*)&Ptile[wv][tl][qq * 16 + r * 4];
            s += (p4.x + p4.y) + (p4.z + p4.w);
        }
        s += __shfl_xor(s, 16, 64);
        s += __shfl_xor(s, 32, 64);
        sbuf[wv][tl] = s;                 // same-value multi-write, benign
        __builtin_amdgcn_wave_barrier();
#pragma unroll
        for (int r = 0; r < 4; ++r) {
            const float4 sv = *(const float4*)&sbuf[wv][r * 4];
            o = fmaf(sv.x, vreg[r * 4 + 0], o);
            o = fmaf(sv.y, vreg[r * 4 + 1], o);
            o = fmaf(sv.z, vreg[r * 4 + 2], o);
            o = fmaf(sv.w, vreg[r * 4 + 3], o);
        }
    }

    // ---- fused RMSNorm over DV (per head = per wave)
    const float ms = wred(o * o) * (1.0f / 64.0f);
    onorm[j] = o * rsqrtf(ms + EPSf) * norm_w[lane];
    __syncthreads();

    // ---- fused output projection: out[n,j] = onorm . W_o[:,j]
    float acc = 0.f;
#pragma unroll 8
    for (int k = 0; k < Dd; ++k)
        acc = fmaf(onorm[k], W_o[(size_t)k * Dd + j], acc);
    out[(size_t)n * Dd + j] = acc;
}

// ---------------------------------------------------------------------------
extern "C" void kernel_launch(void* const* d_in, const int* in_sizes, int n_in,
                              void* d_out, int out_size, void* d_ws, size_t ws_size,
                              hipStream_t stream)
{
    const float* query    = (const float*)d_in[0];   // (8,64,256)
    const float* keyval   = (const float*)d_in[1];   // (8,256,256)
    const int*   mask     = (const int*)  d_in[2];   // (8,256)
    const float* W_cond   = (const float*)d_in[3];   // (256,256)
    const float* W_q      = (const float*)d_in[4];   // (256,256)
    const float* W_k      = (const float*)d_in[5];   // (256,256)
    const float* W_v      = (const float*)d_in[6];   // (256,256)
    const float* W_gk1    = (const float*)d_in[7];   // (256,16)
    const float* W_gk2    = (const float*)d_in[8];   // (16,256)
    const float* b_gk2    = (const float*)d_in[9];   // (256,)
    const float* W_router = (const float*)d_in[10];  // (256,4)
    const float* norm_w   = (const float*)d_in[11];  // (64,)
    const float* W_o      = (const float*)d_in[12];  // (256,256)

    float* out    = (float*)d_out;        // (8,64,256) = 131072
    float* logits = out + Nn * Dd;        // (N*K, 4)   = 524288

    // workspace layout (floats)
    float* p = (float*)d_ws;
    float* Wb   = p; p += Dd * WB;          // 256 x 1088 packed weights
    float* KVb  = p; p += Bb * Kk * WB;     // 2048 x 1088
    float* cond = p; p += Nn * Dd;          // 512 x 256
    float* Cb   = p; p += Nn * WB;          // 512 x 1088

    // 1) pack fused weight matrix (includes Wg = W_gk1 @ W_gk2)
    pack_wb<<<(Dd * WB) / 256, dim3(256), 0, stream>>>(
        W_q, W_k, W_v, W_gk1, W_gk2, W_router, Wb);

    // 2) KVb = keyval @ Wb  AND  cond = query @ W_cond, one launch, 576 blocks
    gemm1<<<576, dim3(256), 0, stream>>>(keyval, query, Wb, W_cond, KVb, cond);

    // 3) Cb = cond @ Wb (512 x 1088 x 256)
    gemm2<<<dim3(WB / 64, Nn / 64), dim3(256), 0, stream>>>(cond, Wb, Cb);

    // 4) router + recurrence + RMSNorm + output projection
    mom_fused<<<Nn, dim3(256), 0, stream>>>(
        KVb, Cb, b_gk2, mask, W_o, norm_w, out, logits);
}